// Round 3
// baseline (170.836 us; speedup 1.0000x reference)
//
#include <hip/hip_runtime.h>
#include <hip/hip_bf16.h>
#include <math.h>

#define D_DIM 2048
#define L_DIM 64
#define E_NUM 64
#define H_DIM 64

typedef float f32x4_t __attribute__((ext_vector_type(4)));
typedef __bf16 bf16x8_t __attribute__((ext_vector_type(8)));

// ---------------- workspace layout (bytes) ----------------
#define WS_UPART 0u
#define WS_META  (128u * 2048u * 4u + 2048u * 4u + 256u)
#define WS_WB    (WS_META + 64u)

// ------- kernel 1: upart[c][d] = sum_{s in 128-row chunk c} x[s,d]*wout[s] ----
__global__ __launch_bounds__(256) void k_upart(const float* __restrict__ x,
                                               const float* __restrict__ wout,
                                               float* __restrict__ upart) {
  const int d4 = (blockIdx.x * 256 + threadIdx.x) * 4;  // gridDim.x == 2
  const int s0 = blockIdx.y * 128;                      // gridDim.y == 64
  const float* xp = x + (size_t)s0 * D_DIM + d4;
  float4 acc0 = make_float4(0.f, 0.f, 0.f, 0.f);
  float4 acc1 = make_float4(0.f, 0.f, 0.f, 0.f);
#pragma unroll 8
  for (int i = 0; i < 128; i += 2) {
    const float w0 = wout[s0 + i];
    const float w1 = wout[s0 + i + 1];
    const float4 a = *reinterpret_cast<const float4*>(xp + (size_t)i * D_DIM);
    const float4 b = *reinterpret_cast<const float4*>(xp + (size_t)(i + 1) * D_DIM);
    acc0.x += a.x * w0; acc0.y += a.y * w0; acc0.z += a.z * w0; acc0.w += a.w * w0;
    acc1.x += b.x * w1; acc1.y += b.y * w1; acc1.z += b.z * w1; acc1.w += b.w * w1;
  }
  acc0.x += acc1.x; acc0.y += acc1.y; acc0.z += acc1.z; acc0.w += acc1.w;
  *reinterpret_cast<float4*>(upart + (size_t)blockIdx.y * D_DIM + d4) = acc0;
}

// ------- kernel 2: fused u-reduce + v = Wg_in u + scores + top2 + softmax ----
__global__ __launch_bounds__(1024) void k_gate_all(
    const float* __restrict__ upart, const float* __restrict__ wg_in,
    const float* __restrict__ wg_lin, int* __restrict__ sel, float* __restrict__ g) {
  __shared__ float uS[D_DIM];
  __shared__ float vS[H_DIM];
  __shared__ float scS[E_NUM];
  const int t = threadIdx.x;
  for (int dd = t; dd < D_DIM; dd += 1024) {
    float s = 0.f;
#pragma unroll 8
    for (int c = 0; c < 64; ++c) s += upart[(size_t)c * D_DIM + dd];
    uS[dd] = s;
  }
  __syncthreads();
  const int w = t >> 6, lane = t & 63;
  for (int hh = w; hh < H_DIM; hh += 16) {
    const float4* wr = reinterpret_cast<const float4*>(wg_in + (size_t)hh * D_DIM);
    float s = 0.f;
#pragma unroll
    for (int j = 0; j < 8; ++j) {
      const float4 a = wr[lane + 64 * j];
      const float* ub = &uS[(lane + 64 * j) * 4];
      s += a.x * ub[0] + a.y * ub[1] + a.z * ub[2] + a.w * ub[3];
    }
#pragma unroll
    for (int off = 32; off; off >>= 1) s += __shfl_down(s, off, 64);
    if (lane == 0) vS[hh] = s;
  }
  __syncthreads();
  if (t < E_NUM) {
    float s = 0.f;
#pragma unroll 8
    for (int hh = 0; hh < H_DIM; ++hh) s += wg_lin[t * H_DIM + hh] * vS[hh];
    scS[t] = s;
  }
  __syncthreads();
  if (t == 0) {
    int b1 = 0; float m1 = scS[0];
    for (int e = 1; e < E_NUM; ++e) { if (scS[e] > m1) { m1 = scS[e]; b1 = e; } }
    int b2 = -1; float m2 = -3.4e38f;
    for (int e = 0; e < E_NUM; ++e) { if (e != b1 && scS[e] > m2) { m2 = scS[e]; b2 = e; } }
    const float e2 = expf(m2 - m1);
    const float g0 = 1.0f / (1.0f + e2);
    sel[0] = b1; sel[1] = b2;
    g[0] = g0; g[1] = 1.0f - g0;
  }
}

// ---------------- kernel 3: cast selected experts to bf16 ----------------
__global__ __launch_bounds__(256) void k_wb(const float* __restrict__ we,
                                            const int* __restrict__ sel,
                                            __hip_bfloat16* __restrict__ wb) {
  const int n = blockIdx.x;  // 128 rows = 2 experts x 64
  const int e = sel[n >> 6];
  const int l = n & 63;
  const float* src = we + ((size_t)e * L_DIM + l) * D_DIM;
  const int t = threadIdx.x;
  const float4 a = reinterpret_cast<const float4*>(src)[2 * t];
  const float4 b = reinterpret_cast<const float4*>(src)[2 * t + 1];
  union { __hip_bfloat16 h[8]; uint4 u; } pk;
  pk.h[0] = __float2bfloat16(a.x); pk.h[1] = __float2bfloat16(a.y);
  pk.h[2] = __float2bfloat16(a.z); pk.h[3] = __float2bfloat16(a.w);
  pk.h[4] = __float2bfloat16(b.x); pk.h[5] = __float2bfloat16(b.y);
  pk.h[6] = __float2bfloat16(b.z); pk.h[7] = __float2bfloat16(b.w);
  reinterpret_cast<uint4*>(wb + (size_t)n * D_DIM)[t] = pk.u;
}

// ---------------- kernel 4: double-buffered bf16 MFMA GEMM + epilogue ------
__device__ __forceinline__ void async_ld16(const void* gp, void* lp) {
  __builtin_amdgcn_global_load_lds(
      (const __attribute__((address_space(1))) unsigned int*)gp,
      (__attribute__((address_space(3))) unsigned int*)lp, 16, 0, 0);
}

__device__ __forceinline__ float gelu_f(float v) {
  return 0.5f * v * (1.0f + erff(v * 0.70710678118654752440f));
}

// Block tile: 16(M) x 128(N), BK=64, 256 threads = 4 waves, 512 blocks = 2/CU.
// Double-buffered via byte OFFSETS into a single __shared__ array (pointer
// arrays of LDS addresses fail gfx950 codegen). A buf stride 2304 B,
// B buf stride 16384 B. B staged async with XOR-swizzled 16B k-chunks.
#define A_OFF 0
#define B_OFF 4608
#define A_STRIDE 2304
#define B_STRIDE 16384
__global__ __launch_bounds__(256) void k_moe_gemm(
    const float* __restrict__ x, const __hip_bfloat16* __restrict__ wb,
    const float* __restrict__ gw, float* __restrict__ out) {
  __shared__ __align__(16) unsigned char lds[2 * 16 * 144 + 2 * 128 * 128];  // 37376

  const int tid = threadIdx.x;
  const int wv = tid >> 6;
  const int lane = tid & 63;
  const int m0 = blockIdx.x * 16;
  const float g0 = gw[0], g1 = gw[1];

  const int ar = tid >> 4, ac = tid & 15;  // A staging: row, quad-of-floats
  const float* gA = x + (size_t)(m0 + ar) * D_DIM + ac * 4;

  const int fr = lane & 15, fq = lane >> 4;

  f32x4_t acc0 = {0.f, 0.f, 0.f, 0.f};
  f32x4_t acc1 = acc0;

#define ISSUE_B(kk, bufo)                                                     \
  {                                                                           \
    const int k0_ = (kk) * 64;                                                \
    _Pragma("unroll") for (int i_ = 0; i_ < 4; ++i_) {                        \
      const int c_ = i_ * 256 + tid;                                          \
      const int r_ = c_ >> 3, p_ = c_ & 7;                                    \
      const int kc_ = p_ ^ (r_ & 7);                                          \
      async_ld16(wb + (size_t)r_ * D_DIM + k0_ + kc_ * 8,                     \
                 lds + B_OFF + (bufo) + c_ * 16);                             \
    }                                                                         \
  }
#define WRITE_A(av, bufo)                                                     \
  {                                                                           \
    union { __hip_bfloat16 h[4]; uint2 u; } pk_;                              \
    pk_.h[0] = __float2bfloat16((av).x); pk_.h[1] = __float2bfloat16((av).y); \
    pk_.h[2] = __float2bfloat16((av).z); pk_.h[3] = __float2bfloat16((av).w); \
    *reinterpret_cast<uint2*>(lds + A_OFF + (bufo) + ar * 144 + ac * 8) = pk_.u; \
  }

  // prologue: stage tile 0 into buffer 0
  ISSUE_B(0, 0);
  {
    const float4 a0 = *reinterpret_cast<const float4*>(gA);
    WRITE_A(a0, 0);
  }
  __syncthreads();

  for (int kk = 0; kk < 32; ++kk) {
    const int curA = (kk & 1) * A_STRIDE, nxtA = ((kk & 1) ^ 1) * A_STRIDE;
    const int curB = (kk & 1) * B_STRIDE, nxtB = ((kk & 1) ^ 1) * B_STRIDE;
    float4 aN = make_float4(0.f, 0.f, 0.f, 0.f);
    const bool more = (kk + 1) < 32;
    if (more) {
      ISSUE_B(kk + 1, nxtB);
      aN = *reinterpret_cast<const float4*>(gA + (kk + 1) * 64);
    }
    union fragu { uint4 u; bf16x8_t v; };
    fragu af[2], bfr[2][2];
#pragma unroll
    for (int ks = 0; ks < 2; ++ks)
      af[ks].u = *reinterpret_cast<const uint4*>(
          lds + A_OFF + curA + fr * 144 + ks * 64 + fq * 16);
#pragma unroll
    for (int nt = 0; nt < 2; ++nt)
#pragma unroll
      for (int ks = 0; ks < 2; ++ks) {
        const int r = wv * 32 + nt * 16 + fr;
        const int kg = ks * 4 + fq;
        bfr[nt][ks].u = *reinterpret_cast<const uint4*>(
            lds + B_OFF + curB + r * 128 + ((kg ^ (r & 7)) * 16));
      }
    acc0 = __builtin_amdgcn_mfma_f32_16x16x32_bf16(af[0].v, bfr[0][0].v, acc0, 0, 0, 0);
    acc0 = __builtin_amdgcn_mfma_f32_16x16x32_bf16(af[1].v, bfr[0][1].v, acc0, 0, 0, 0);
    acc1 = __builtin_amdgcn_mfma_f32_16x16x32_bf16(af[0].v, bfr[1][0].v, acc1, 0, 0, 0);
    acc1 = __builtin_amdgcn_mfma_f32_16x16x32_bf16(af[1].v, bfr[1][1].v, acc1, 0, 0, 0);
    if (more) WRITE_A(aN, nxtA);
    __syncthreads();
  }

  // ---- epilogue: z tile [16][132] f32 overlays staging LDS ----
  float* z = reinterpret_cast<float*>(lds);
  {
    const int colbase = wv * 32 + fr;
#pragma unroll
    for (int reg = 0; reg < 4; ++reg) {
      const int r0 = fq * 4 + reg;
      z[r0 * 132 + colbase]      = acc0[reg];
      z[r0 * 132 + colbase + 16] = acc1[reg];
    }
  }
  __syncthreads();
  float* ps = reinterpret_cast<float*>(lds + 16 * 132 * 4);  // [16][16]
  {
    const int r = tid >> 4, seg = tid & 15;
    float s = 0.f;
#pragma unroll
    for (int i2 = 0; i2 < 8; ++i2) {
      const float t2 = z[r * 132 + seg * 8 + i2];
      s += t2 * t2;
    }
    ps[r * 16 + seg] = s;
  }
  __syncthreads();
  {
    const int r = tid >> 4, j = tid & 15;
    float s0 = 0.f, s1 = 0.f;
#pragma unroll
    for (int i2 = 0; i2 < 8; ++i2) { s0 += ps[r * 16 + i2]; s1 += ps[r * 16 + 8 + i2]; }
    const float i0 = 1.0f / fmaxf(sqrtf(s0), 1e-12f);
    const float i1 = 1.0f / fmaxf(sqrtf(s1), 1e-12f);
    float o[4];
#pragma unroll
    for (int i2 = 0; i2 < 4; ++i2) {
      const int c = j * 4 + i2;
      o[i2] = g0 * gelu_f(z[r * 132 + c] * i0) + g1 * gelu_f(z[r * 132 + 64 + c] * i1);
    }
    *reinterpret_cast<float4*>(out + (size_t)(m0 + r) * 64 + j * 4) =
        make_float4(o[0], o[1], o[2], o[3]);
  }
#undef ISSUE_B
#undef WRITE_A
}

// ---------------- launch ----------------
extern "C" void kernel_launch(void* const* d_in, const int* in_sizes, int n_in,
                              void* d_out, int out_size, void* d_ws, size_t ws_size,
                              hipStream_t stream) {
  (void)in_sizes; (void)n_in; (void)out_size; (void)ws_size;
  const float* x      = (const float*)d_in[0];
  const float* wg_in  = (const float*)d_in[1];
  const float* wg_lin = (const float*)d_in[2];
  const float* wg_out = (const float*)d_in[3];
  const float* we     = (const float*)d_in[4];
  float* out = (float*)d_out;
  char* ws = (char*)d_ws;

  float* upart = (float*)(ws + WS_UPART);
  int*   sel   = (int*)(ws + WS_META);
  float* g     = (float*)(ws + WS_META + 8);
  __hip_bfloat16* wb = (__hip_bfloat16*)(ws + WS_WB);

  k_upart   <<<dim3(2, 64), 256, 0, stream>>>(x, wg_out, upart);
  k_gate_all<<<1, 1024, 0, stream>>>(upart, wg_in, wg_lin, sel, g);
  k_wb      <<<128, 256, 0, stream>>>(we, sel, wb);
  k_moe_gemm<<<512, 256, 0, stream>>>(x, wb, g, out);
}